// Round 6
// baseline (202.969 us; speedup 1.0000x reference)
//
#include <hip/hip_runtime.h>
#include <math.h>

// Input [32, 3, 512, 512] f32 -> output [32, 27, 512, 512] f32.
// Channel-per-WAVE structure: each block (9 waves, 576 thr) stages a
// 1024-fx4 input segment into LDS once; wave w writes channels 3w..3w+2,
// each as ONE contiguous 16 KB run (16 back-to-back 1 KB wave-stores).
// Goal: fill-like single-stream-per-wave DRAM behavior, read-once/write-once.
#define P4    65536          // fx4 groups per 512x512 plane
#define SEG   1024           // fx4 groups per block segment (16 KB/channel)
#define NCH   27
#define BATCH 32
#define NW    9              // waves per block: 27 channels / 3 per wave
#define BLOCK (NW * 64)      // 576 threads

typedef float fx4 __attribute__((ext_vector_type(4)));

// f: 0 = identity, 1 = cos, 2 = sin  (wave-uniform selector)
__device__ __forceinline__ fx4 apply_f(int f, fx4 x) {
    if (f == 0) return x;
    fx4 r;
    if (f == 1) {
        r.x = __cosf(x.x); r.y = __cosf(x.y); r.z = __cosf(x.z); r.w = __cosf(x.w);
    } else {
        r.x = __sinf(x.x); r.y = __sinf(x.y); r.z = __sinf(x.z); r.w = __sinf(x.w);
    }
    return r;
}

__global__ __launch_bounds__(BLOCK) void sclayer_58746562675072_kernel(
        const fx4* __restrict__ in, fx4* __restrict__ out) {
    __shared__ fx4 xs[3 * SEG];          // 48 KB: input segment, [c][j]

    const int blk = blockIdx.x;          // 0..2047
    const int b   = blk >> 6;            // 64 segments per plane
    const int seg = blk & 63;

    const fx4* inb = in + (size_t)b * (3 * P4) + seg * SEG;

    // Stage input segment (3 x 16 KB) into LDS, coalesced.
    for (int t = threadIdx.x; t < 3 * SEG; t += BLOCK) {
        const int c = t >> 10;           // SEG == 1024
        const int j = t & (SEG - 1);
        xs[t] = inb[c * P4 + j];
    }
    __syncthreads();

    const int w    = threadIdx.x >> 6;   // wave id 0..8 (uniform per wave)
    const int lane = threadIdx.x & 63;
    fx4* outbase = out + (size_t)b * (NCH * P4) + seg * SEG;

    #pragma unroll
    for (int k0 = 0; k0 < 3; ++k0) {
        const int ch = 3 * w + k0;       // wave-uniform channel

        // Decode channel -> (s0, f0) [, (s1, f1)]; torch pair order
        // (i in 0..8, j in range(i, 9, 3)) for product channels 9..26.
        int s0, f0, s1 = -1, f1 = 0;
        if (ch < 9) {
            s0 = ch % 3; f0 = ch / 3;
        } else {
            int t = ch - 9, i = 0;
            while (true) {
                int cnt = ((8 - i) / 3) + 1;   // pairs per i: 3,3,3,2,2,2,1,1,1
                if (t < cnt) break;
                t -= cnt; ++i;
            }
            int j = i + 3 * t;
            s0 = i % 3; f0 = i / 3;
            s1 = j % 3; f1 = j / 3;
        }

        fx4* op = outbase + (size_t)ch * P4;
        const bool prod = (s1 >= 0);
        #pragma unroll 4
        for (int i = lane; i < SEG; i += 64) {
            fx4 v = apply_f(f0, xs[s0 * SEG + i]);
            if (prod) {
                fx4 u = apply_f(f1, xs[s1 * SEG + i]);
                v.x *= u.x; v.y *= u.y; v.z *= u.z; v.w *= u.w;
            }
            op[i] = v;                   // 1 KB wave-burst; 16 consecutive
        }                                // bursts = 16 KB sequential run
    }
}

extern "C" void kernel_launch(void* const* d_in, const int* in_sizes, int n_in,
                              void* d_out, int out_size, void* d_ws, size_t ws_size,
                              hipStream_t stream) {
    const fx4* in  = (const fx4*)d_in[0];
    fx4*       out = (fx4*)d_out;
    const int grid = BATCH * (P4 / SEG);     // 32 * 64 = 2048 blocks
    sclayer_58746562675072_kernel<<<grid, BLOCK, 0, stream>>>(in, out);
}